// Round 2
// 302.830 us; speedup vs baseline: 1.0203x; 1.0203x over previous
//
#include <hip/hip_runtime.h>
#include <math.h>

#define BB 16
#define TT 2048
#define DD 1024
#define THRESH 0.95f
#define RPB 8   // output rows per gather block (TT/RPB = 256 chunks per batch)

typedef float nt4 __attribute__((ext_vector_type(4)));   // native vec4 for nontemporal builtins

__device__ __forceinline__ void nt_store4(const float4& v, float4* p) {
    nt4 x = {v.x, v.y, v.z, v.w};
    __builtin_nontemporal_store(x, (nt4*)p);
}

// ---------------- Kernel 1: projection + sigmoid + mask ----------------
__global__ __launch_bounds__(256) void proj_kernel(
    const float* __restrict__ hs, const float* __restrict__ hs_mask,
    const float* __restrict__ w, const float* __restrict__ bias,
    float* __restrict__ alphas)
{
    int row  = blockIdx.x * 4 + (threadIdx.x >> 6);   // b*T + t
    int lane = threadIdx.x & 63;
    const float4* hp = (const float4*)(hs + (size_t)row * DD);
    const float4* wp = (const float4*)w;
    float sum = 0.f;
#pragma unroll
    for (int j = 0; j < 4; ++j) {
        float4 h4 = hp[lane + 64 * j];
        float4 w4 = wp[lane + 64 * j];
        sum += h4.x * w4.x + h4.y * w4.y + h4.z * w4.z + h4.w * w4.w;
    }
#pragma unroll
    for (int off = 32; off; off >>= 1) sum += __shfl_down(sum, off, 64);
    if (lane == 0) {
        float x  = sum + bias[0];
        float al = 1.f / (1.f + expf(-x));   // expf: fire decisions are rounding-sensitive
        alphas[row] = al * hs_mask[row];
    }
}

// ---------------- Kernel 2: integrate-and-fire scan (serial-exact) ----------------
// One wave per batch. 8 named VGPRs x 64 lanes hold 512 alphas per outer pass.
// Serial fp32 chain bit-identical to the reference; lane j captures step j's
// outputs via lane==j cndmask. Per 64-step group: one coalesced cur store and
// one __ballot(pv > THRESH) fire mask.
// Also writes out_mask (moved out of gather so gather only streams frames).

#define SCAN_GROUP(RREG, GIDX)                                                \
    {                                                                         \
        float cv = 0.f, pv = 0.f;                                             \
        _Pragma("unroll 16")                                                  \
        for (int j = 0; j < 64; ++j) {                                        \
            float a = __int_as_float(                                         \
                __builtin_amdgcn_readlane(__float_as_int(RREG), j));          \
            float pre  = integ + a;              /* chain: v_add */           \
            bool  fire = pre > THRESH;           /* chain: v_cmp */           \
            float c    = fire ? dist : a;                                     \
            integ      = fire ? pre - 1.f : pre; /* chain: v_cndmask */       \
            dist       = 1.f - integ;                                         \
            bool sel   = (lane == j);                                         \
            cv = sel ? c   : cv;                                              \
            pv = sel ? pre : pv;                                              \
        }                                                                     \
        cp[(GIDX) * 64 + lane] = cv;                                          \
        unsigned long long bm = __ballot(pv > THRESH);                        \
        gmask = (lane == (GIDX)) ? bm : gmask;                                \
    }

__global__ __launch_bounds__(64) void scan_kernel(
    const float* __restrict__ alphas, float* __restrict__ cur,
    int* __restrict__ fire_times, int* __restrict__ n_fires,
    int* __restrict__ len_labels, float* __restrict__ out_mask)
{
    int b    = blockIdx.x;
    int lane = threadIdx.x;                  // 0..63, one wave
    const float* ap = alphas + (size_t)b * TT;
    float*       cp = cur    + (size_t)b * TT;

    unsigned long long gmask = 0ull;         // lane g: fire mask of steps [g*64,(g+1)*64)
    float integ = 0.f, dist = 1.f;
    double dsum = 0.0;

    for (int outer = 0; outer < 4; ++outer) {
        int base = outer * 512 + lane;
        float r0 = ap[base +   0];
        float r1 = ap[base +  64];
        float r2 = ap[base + 128];
        float r3 = ap[base + 192];
        float r4 = ap[base + 256];
        float r5 = ap[base + 320];
        float r6 = ap[base + 384];
        float r7 = ap[base + 448];
        dsum += (double)r0 + (double)r1 + (double)r2 + (double)r3
              + (double)r4 + (double)r5 + (double)r6 + (double)r7;
        int gb = outer * 8;
        SCAN_GROUP(r0, gb + 0)
        SCAN_GROUP(r1, gb + 1)
        SCAN_GROUP(r2, gb + 2)
        SCAN_GROUP(r3, gb + 3)
        SCAN_GROUP(r4, gb + 4)
        SCAN_GROUP(r5, gb + 5)
        SCAN_GROUP(r6, gb + 6)
        SCAN_GROUP(r7, gb + 7)
    }

    // len_labels: wave double-reduce (order-insensitive; round tolerance huge)
#pragma unroll
    for (int off = 32; off; off >>= 1) dsum += __shfl_down(dsum, off, 64);
    int len = __double2int_rn(dsum);         // valid on lane 0
    len = __shfl(len, 0, 64);                // broadcast to all lanes
    if (lane == 0) len_labels[b] = len;

    // out_mask: coalesced 0/1 writes, 32 per lane
    float* mp = out_mask + (size_t)b * TT;
#pragma unroll
    for (int j = 0; j < TT / 64; ++j)
        mp[j * 64 + lane] = ((j * 64 + lane) < len) ? 1.f : 0.f;

    // Expand fire masks -> fire_times (order-preserving prefix over 32 groups)
    int cnt  = __popcll(gmask);
    int pref = cnt;
#pragma unroll
    for (int off = 1; off < 64; off <<= 1) {
        int y = __shfl_up(pref, off, 64);
        if (lane >= off) pref += y;
    }
    int pos = pref - cnt;
    unsigned long long m = gmask;
    int baset = lane * 64;
    int* fp = fire_times + (size_t)b * TT;
    while (m) {
        int j = __ffsll(m) - 1;
        fp[pos++] = baset + j;
        m &= m - 1;
    }
    if (lane == 63) n_fires[b] = pref;
}

// ---------------- Kernel 3: chunked streaming gather ----------------
// One block owns RPB consecutive output rows of one batch. Fire times are
// strictly increasing, so the RPB segments form ONE contiguous t-range: each
// hs frame is read exactly once (boundary frame for row r+1 = last frame of
// row r, carried in registers — no re-read). Rows statically unrolled (no
// runtime-indexed register arrays), one accumulator live at a time.
// Out is never re-read -> nontemporal stores (keeps hs resident in L3 for
// this second pass).
__global__ __launch_bounds__(256) void gather_kernel(
    const float* __restrict__ hs, const float* __restrict__ alphas,
    const float* __restrict__ cur, const int* __restrict__ fire_times,
    const int* __restrict__ n_fires, float* __restrict__ out)
{
    int chunk = blockIdx.x;          // b * (TT/RPB) + c
    int b  = chunk >> 8;             // TT/RPB = 256
    int r0 = (chunk & 255) * RPB;
    int ti = threadIdx.x;            // 0..255, covers D via float4
    int nf = n_fires[b];

    float4* ob = (float4*)(out + ((size_t)b * TT + r0) * DD);

    if (r0 >= nf) {                  // whole chunk past last fire: zeros
        float4 z = {0.f, 0.f, 0.f, 0.f};
#pragma unroll
        for (int i = 0; i < RPB; ++i)
            nt_store4(z, &ob[i * 256 + ti]);
        return;
    }

    const int*    ft  = fire_times + (size_t)b * TT;
    const float*  al  = alphas     + (size_t)b * TT;
    const float*  cu  = cur        + (size_t)b * TT;
    const float4* hsb = (const float4*)(hs + (size_t)b * TT * DD);

    int    t;
    float4 hprev = {0.f, 0.f, 0.f, 0.f};   // last frame of previous row's segment
    float  wprev = 0.f;                    // its boundary weight (alpha - cur)
    bool   have_prev;
    if (r0 == 0) {
        t = 0;
        have_prev = false;                 // row 0 has no boundary term
    } else {
        int tp = ft[r0 - 1];
        t = tp + 1;
        hprev = hsb[(size_t)tp * 256 + ti];
        wprev = al[tp] - cu[tp];
        have_prev = true;
    }

#pragma unroll
    for (int i = 0; i < RPB; ++i) {
        int r = r0 + i;
        float4 a = {0.f, 0.f, 0.f, 0.f};
        if (r < nf) {
            if (have_prev) {               // boundary term FIRST (matches reference order)
                a.x = wprev * hprev.x; a.y = wprev * hprev.y;
                a.z = wprev * hprev.z; a.w = wprev * hprev.w;
            }
            int te = ft[r];
            for (;;) {                     // stream segment frames in ascending t
                float4 h  = hsb[(size_t)t * 256 + ti];
                float  cw = cu[t];
                a.x += cw * h.x; a.y += cw * h.y;
                a.z += cw * h.z; a.w += cw * h.w;
                if (t == te) {
                    wprev = al[t] - cw;    // boundary weight for next row
                    hprev = h;             // frame stays in registers
                    ++t;
                    break;
                }
                ++t;
            }
            have_prev = true;
        }
        nt_store4(a, &ob[i * 256 + ti]);
    }
}

extern "C" void kernel_launch(void* const* d_in, const int* in_sizes, int n_in,
                              void* d_out, int out_size, void* d_ws, size_t ws_size,
                              hipStream_t stream) {
    const float* hs      = (const float*)d_in[0];   // [B,T,D]
    const float* hs_mask = (const float*)d_in[1];   // [B,1,T]
    const float* w       = (const float*)d_in[2];   // [D]
    const float* bias    = (const float*)d_in[3];   // scalar

    float* out      = (float*)d_out;                       // [B,T,D]
    float* out_mask = out + (size_t)BB * TT * DD;          // [B,1,T] as 0/1 floats

    float* alphas     = (float*)d_ws;                      // B*T floats
    float* cur        = alphas + BB * TT;                  // B*T floats
    int*   fire_times = (int*)(cur + BB * TT);             // B*T ints
    int*   n_fires    = fire_times + BB * TT;              // B ints
    int*   len_labels = n_fires + BB;                      // B ints

    proj_kernel<<<BB * TT / 4, 256, 0, stream>>>(hs, hs_mask, w, bias, alphas);
    scan_kernel<<<BB, 64, 0, stream>>>(alphas, cur, fire_times, n_fires,
                                       len_labels, out_mask);
    gather_kernel<<<BB * (TT / RPB), 256, 0, stream>>>(hs, alphas, cur, fire_times,
                                                       n_fires, out);
}